// Round 3
// baseline (156.750 us; speedup 1.0000x reference)
//
#include <hip/hip_runtime.h>

// B=32, C=128, H=W=32, kern=2 -> pooled h=w=16
// Single fused kernel: avgpool + var + z + pairwise Gaussian mixture
// log-densities + full reduction (last-block-done pattern).
// out = B * sum_{i,c,h,w} [ log(mean_j dA(i,j)+eps) - log(mean_j dB(i,j)+eps) ]
//
// 2-param form: s = sqrt(log2e/(2 var)), then
//   d(i,j) = 1.17741002*s_j * exp2(-(z-mu_j)^2 * s_j^2)
// 1.17741002/32 folds into one scalar applied after the j-sum.
// LDS j-loop reads are wave-uniform-per-half b128 broadcasts (conflict-free,
// served at broadcast rate) -> kernel is HBM-bound on the 68 MB input read.

#define GKL_EPS 1e-6f

__global__ __launch_bounds__(256) void gkl_main(
    const float* __restrict__ muA, const float* __restrict__ lvA,
    const float* __restrict__ muB, const float* __restrict__ lvB,
    const float* __restrict__ eps, double* __restrict__ ws,
    unsigned int* __restrict__ cnt, float* __restrict__ out)
{
    // floats: Q side A [0,1024)+pad, side B [1028,2052)+pad, zs [2056,2600), wsum [2600,2604)
    // Q per side: [jpair 16][pixel 16][4] = {s(2jj), mu(2jj), s(2jj+1), mu(2jj+1)}
    // side stride 1028 floats => +4 bank shift so the two half-wave broadcast
    // addresses hit disjoint banks.
    __shared__ float sh[2*1028 + 32*17 + 4];
    __shared__ int lastFlag;
    __shared__ double part[4];

    const int bid = blockIdx.x;        // 0..2047 = C*16
    const int c   = bid >> 4;
    const int h   = bid & 15;
    const int t   = threadIdx.x;
    const int w   = t & 15;
    const int b0  = t >> 4;
    const int row0 = 2*h, col0 = 2*w;

    // ---- Phase 1: pooled params (each thread: 2 batch rows, both sides) ----
    #pragma unroll
    for (int rep = 0; rep < 2; ++rep) {
        const int b = b0 + rep*16;
        const size_t base = ((size_t)(b*128 + c)*32 + row0)*32 + col0;
        const int qidx = ((b >> 1)*16 + w)*4 + (b & 1)*2;   // float offset in Q

        // side A
        float2 m0 = *(const float2*)(muA + base);
        float2 m1 = *(const float2*)(muA + base + 32);
        float2 l0 = *(const float2*)(lvA + base);
        float2 l1 = *(const float2*)(lvA + base + 32);
        float mu  = (m0.x + m0.y + m1.x + m1.y) * 0.25f;
        float var = (__expf(l0.x) + __expf(l0.y) + __expf(l1.x) + __expf(l1.y)) * 0.0625f;
        float s   = __builtin_amdgcn_sqrtf(0.72134752f * __builtin_amdgcn_rcpf(var));
        *(float2*)(sh + qidx) = make_float2(s, mu);
        float ev = eps[((b*128 + c)*16 + h)*16 + w];
        sh[2*1028 + b*17 + w] = fmaf(__builtin_amdgcn_sqrtf(var), ev, mu);  // z

        // side B
        float2 n0 = *(const float2*)(muB + base);
        float2 n1 = *(const float2*)(muB + base + 32);
        float2 k0 = *(const float2*)(lvB + base);
        float2 k1 = *(const float2*)(lvB + base + 32);
        float mub  = (n0.x + n0.y + n1.x + n1.y) * 0.25f;
        float varb = (__expf(k0.x) + __expf(k0.y) + __expf(k1.x) + __expf(k1.y)) * 0.0625f;
        float sb   = __builtin_amdgcn_sqrtf(0.72134752f * __builtin_amdgcn_rcpf(varb));
        *(float2*)(sh + 1028 + qidx) = make_float2(sb, mub);
    }
    __syncthreads();

    // ---- Phase 2: wave-per-pixel pairwise loop, 2 j's per b128 broadcast ----
    const int lane = t & 63;
    const int wv   = t >> 6;           // wave 0..3
    const int i    = lane & 31;        // sample index
    const int side = lane >> 5;        // 0 = mixture A, 1 = mixture B
    const float4* __restrict__ Qs = (const float4*)(sh + side*1028);
    const float* __restrict__ zp  = sh + 2*1028;
    float* __restrict__ wsum      = sh + 2*1028 + 32*17;

    float tot = 0.f;
    #pragma unroll
    for (int q = 0; q < 4; ++q) {
        const int p  = wv*4 + q;       // pixel for this wave
        const float zi = zp[i*17 + p]; // 17-stride: conflict-free column read
        float acc0 = 0.f, acc1 = 0.f;
        #pragma unroll
        for (int jj = 0; jj < 16; ++jj) {
            float4 f = Qs[jj*16 + p];  // wave-uniform per half -> broadcast
            float d0 = zi - f.y, d1 = zi - f.w;
            float s0 = f.x,      s1 = f.z;
            acc0 = fmaf(s0, exp2f(-(d0*d0*(s0*s0))), acc0);
            acc1 = fmaf(s1, exp2f(-(d1*d1*(s1*s1))), acc1);
        }
        // 1.17741002 (=sqrt(2 ln2)) / 32 = 0.036794063
        float lg = __logf(fmaf(acc0 + acc1, 0.036794063f, GKL_EPS));
        tot += side ? -lg : lg;
    }

    #pragma unroll
    for (int o = 32; o; o >>= 1) tot += __shfl_xor(tot, o, 64);
    if (lane == 0) wsum[wv] = tot;
    __syncthreads();

    // ---- Last-block-done final reduction ----
    if (t == 0) {
        ws[bid] = (double)wsum[0] + (double)wsum[1] + (double)wsum[2] + (double)wsum[3];
        __threadfence();                         // partial visible device-wide
        unsigned int old = atomicAdd(cnt, 1u);   // device-scope RMW
        lastFlag = (old == 2047u);
    }
    __syncthreads();
    if (lastFlag) {
        __threadfence();                         // acquire: see all partials
        double s = 0.0;
        for (int k = t; k < 2048; k += 256) s += ws[k];
        #pragma unroll
        for (int o = 32; o; o >>= 1) s += __shfl_xor(s, o, 64);
        if ((t & 63) == 0) part[t >> 6] = s;
        __syncthreads();
        if (t == 0) out[0] = (float)(32.0 * (part[0] + part[1] + part[2] + part[3]));
    }
}

extern "C" void kernel_launch(void* const* d_in, const int* in_sizes, int n_in,
                              void* d_out, int out_size, void* d_ws, size_t ws_size,
                              hipStream_t stream) {
    const float* muA = (const float*)d_in[0];
    const float* lvA = (const float*)d_in[1];
    const float* muB = (const float*)d_in[2];
    const float* lvB = (const float*)d_in[3];
    const float* ep  = (const float*)d_in[4];
    double* ws        = (double*)d_ws;                      // 2048 doubles = 16 KB
    unsigned int* cnt = (unsigned int*)((char*)d_ws + 16384);
    float* out        = (float*)d_out;

    hipMemsetAsync(cnt, 0, sizeof(unsigned int), stream);   // init-agnostic counter
    gkl_main<<<2048, 256, 0, stream>>>(muA, lvA, muB, lvB, ep, ws, cnt, out);
}

// Round 4
// 117.956 us; speedup vs baseline: 1.3289x; 1.3289x over previous
//
#include <hip/hip_runtime.h>

// B=32, C=128, H=W=32, kern=2 -> pooled h=w=16
// Two kernels: fused pool+params+pairwise+block-reduce, then tiny final reduce.
// out = B * sum_{i,c,h,w} [ log(mean_j dA(i,j)+eps) - log(mean_j dB(i,j)+eps) ]
//
// Per-j density folded to ONE exp2 with 3 params {mu, c2, lg2s}:
//   d_j = 1.17741002 * exp2( c2_j*(z-mu_j)^2 + lg2s_j ),  c2 = -log2e/(2v), lg2s = log2(s)
// j-loop: per 4 j's = 3 uniform ds_read_b128 (SoA float4) + 16 VALU + 4 exp2,
// all LDS reads via one base VGPR + immediate offsets.

#define GKL_EPS 1e-6f

// LDS float layout:
//   Q: side*1540 + (g*3 + param)*64 + p*4 + e     (side 0/1, g 0..7, param 0..2)
//      param 0 = mu[4j], 1 = c2[4j], 2 = lg2s[4j]; side stride 1540 = 4-bank skew
//   zs: 3080 + b*17 + p    (padded stride 17)
//   wsum: 3624..3627
__global__ __launch_bounds__(256) void gkl_main(
    const float* __restrict__ muA, const float* __restrict__ lvA,
    const float* __restrict__ muB, const float* __restrict__ lvB,
    const float* __restrict__ eps, double* __restrict__ ws)
{
    __shared__ float sh[3628];

    const int bid = blockIdx.x;        // 0..2047 = C*16
    const int c   = bid >> 4;
    const int h   = bid & 15;
    const int t   = threadIdx.x;
    const int w   = t & 15;
    const int b0  = t >> 4;

    // ---- Phase 1: pooled params (each thread: 2 batch rows, both sides) ----
    #pragma unroll
    for (int rep = 0; rep < 2; ++rep) {
        const int b = b0 + rep*16;                         // = mixture index j
        const int base = ((b*128 + c)*32 + 2*h)*32 + 2*w;  // int addressing
        const int qw = ((b >> 2)*3)*64 + w*4 + (b & 3);    // scatter slot

        // ---- side A ----
        float2 m0 = *(const float2*)(muA + base);
        float2 m1 = *(const float2*)(muA + base + 32);
        float2 l0 = *(const float2*)(lvA + base);
        float2 l1 = *(const float2*)(lvA + base + 32);
        float mu  = (m0.x + m0.y + m1.x + m1.y) * 0.25f;
        float var = (__expf(l0.x) + __expf(l0.y) + __expf(l1.x) + __expf(l1.y)) * 0.0625f;
        float c2  = -0.72134752f * __builtin_amdgcn_rcpf(var);          // -log2e/(2v)
        float ls  = fmaf(-0.5f, __builtin_amdgcn_logf(var), -0.2356196f); // log2(s)
        sh[qw]       = mu;
        sh[qw + 64]  = c2;
        sh[qw + 128] = ls;
        float ev = eps[((b*128 + c)*16 + h)*16 + w];
        sh[3080 + b*17 + w] = fmaf(__builtin_amdgcn_sqrtf(var), ev, mu);  // z

        // ---- side B ----
        float2 n0 = *(const float2*)(muB + base);
        float2 n1 = *(const float2*)(muB + base + 32);
        float2 k0 = *(const float2*)(lvB + base);
        float2 k1 = *(const float2*)(lvB + base + 32);
        float mub  = (n0.x + n0.y + n1.x + n1.y) * 0.25f;
        float varb = (__expf(k0.x) + __expf(k0.y) + __expf(k1.x) + __expf(k1.y)) * 0.0625f;
        float c2b  = -0.72134752f * __builtin_amdgcn_rcpf(varb);
        float lsb  = fmaf(-0.5f, __builtin_amdgcn_logf(varb), -0.2356196f);
        sh[1540 + qw]       = mub;
        sh[1540 + qw + 64]  = c2b;
        sh[1540 + qw + 128] = lsb;
    }
    __syncthreads();

    // ---- Phase 2: wave-per-pixel, 4 j's per 3 b128 broadcasts ----
    const int lane = t & 63;
    const int wv   = t >> 6;           // wave 0..3
    const int i    = lane & 31;        // sample index
    const int side = lane >> 5;        // 0 = mixture A, 1 = mixture B
    const float* __restrict__ Qb = sh + side*1540;
    const float* __restrict__ zp = sh + 3080;
    float* __restrict__ wsum     = sh + 3624;

    float tot = 0.f;
    #pragma unroll
    for (int q = 0; q < 4; ++q) {
        const int p  = wv*4 + q;           // pixel for this wave
        const float zi = zp[i*17 + p];     // broadcast-pair across halves: free
        const float* base = Qb + p*4;      // ONE address reg; all reads imm-offset
        float accA = 0.f, accB = 0.f;
        #pragma unroll
        for (int g = 0; g < 8; ++g) {
            float4 m  = *(const float4*)(base + g*192);
            float4 cc = *(const float4*)(base + g*192 + 64);
            float4 ll = *(const float4*)(base + g*192 + 128);
            float d0 = zi - m.x, d1 = zi - m.y, d2 = zi - m.z, d3 = zi - m.w;
            accA += exp2f(fmaf(d0*d0, cc.x, ll.x));
            accB += exp2f(fmaf(d1*d1, cc.y, ll.y));
            accA += exp2f(fmaf(d2*d2, cc.z, ll.z));
            accB += exp2f(fmaf(d3*d3, cc.w, ll.w));
        }
        // 1.17741002 (=sqrt(2 ln2)) / 32
        float lg = __logf(fmaf(accA + accB, 0.036794063f, GKL_EPS));
        tot += side ? -lg : lg;
    }

    #pragma unroll
    for (int o = 32; o; o >>= 1) tot += __shfl_xor(tot, o, 64);
    if (lane == 0) wsum[wv] = tot;
    __syncthreads();
    if (t == 0)
        ws[bid] = (double)wsum[0] + (double)wsum[1] + (double)wsum[2] + (double)wsum[3];
}

__global__ __launch_bounds__(256) void gkl_final(
    const double* __restrict__ ws, float* __restrict__ out)
{
    __shared__ double part[4];
    const int t = threadIdx.x;
    double s = 0.0;
    for (int k = t; k < 2048; k += 256) s += ws[k];
    #pragma unroll
    for (int o = 32; o; o >>= 1) s += __shfl_xor(s, o, 64);
    if ((t & 63) == 0) part[t >> 6] = s;
    __syncthreads();
    if (t == 0) out[0] = (float)(32.0 * (part[0] + part[1] + part[2] + part[3]));
}

extern "C" void kernel_launch(void* const* d_in, const int* in_sizes, int n_in,
                              void* d_out, int out_size, void* d_ws, size_t ws_size,
                              hipStream_t stream) {
    const float* muA = (const float*)d_in[0];
    const float* lvA = (const float*)d_in[1];
    const float* muB = (const float*)d_in[2];
    const float* lvB = (const float*)d_in[3];
    const float* ep  = (const float*)d_in[4];
    double* ws = (double*)d_ws;          // 2048 doubles = 16 KB
    float* out = (float*)d_out;

    gkl_main<<<2048, 256, 0, stream>>>(muA, lvA, muB, lvB, ep, ws);
    gkl_final<<<1, 256, 0, stream>>>(ws, out);
}